// Round 9
// baseline (183.143 us; speedup 1.0000x reference)
//
#include <hip/hip_runtime.h>

typedef unsigned short ushort;
typedef __attribute__((ext_vector_type(8))) short bf16x8;
typedef __attribute__((ext_vector_type(4))) float f32x4;
typedef __attribute__((ext_vector_type(4))) ushort us4;

#define NBATCH 32
#define ICN 256
#define OCN 256
#define HSZ 56
#define WSZ 56
#define HP 58
#define SPAT (HP*HP)            /* 3364 */
#define KTOT 2304               /* 9*256, k = (kh*3+kw)*256 + ic */
#define MTOT (NBATCH*HSZ*WSZ)   /* 100352 */
#define NT   (KTOT/64)          /* 36 K-tiles of BK=64 */

#define XP_BYTES ((size_t)NBATCH*SPAT*ICN*2)    /* 55,115,776 */
#define WD_BYTES ((size_t)OCN*KTOT*4)           /* 2,359,296  */

__device__ __forceinline__ ushort f2bf(float f) {
  union { float f; unsigned u; } c; c.f = f;
  unsigned r = c.u + 0x7FFFu + ((c.u >> 16) & 1u);
  return (ushort)(r >> 16);
}

// x [N][IC][56][56] f32 -> xp [N][58][58][IC] bf16, halo rows/cols written as 0
__global__ void k_transpose(const float* __restrict__ x, ushort* __restrict__ xp) {
  __shared__ float tile[ICN*57];   // stride 57: conflict-free transpose read
  int h = blockIdx.x, n = blockIdx.y;          // h = padded row 0..57
  ushort* dst = xp + ((size_t)n*SPAT + (size_t)h*HP)*ICN;
  if (h == 0 || h == HP-1) {
    for (int e = threadIdx.x; e < HP*ICN/4; e += 256) ((us4*)dst)[e] = (us4){0,0,0,0};
    return;
  }
  const float* src = x + ((size_t)n*ICN*HSZ*WSZ) + (size_t)(h-1)*WSZ;
  for (int e = threadIdx.x; e < ICN*WSZ; e += 256) {
    int ic = e / WSZ, w = e - ic*WSZ;                 // w fastest -> coalesced read
    tile[ic*57 + w] = src[(size_t)ic*(HSZ*WSZ) + w];
  }
  __syncthreads();
  for (int e = threadIdx.x; e < ICN*HP; e += 256) {   // e = w*256+ic, w=0..57
    int w = e >> 8, ic = e & 255;
    dst[e] = (w == 0 || w == HP-1) ? (ushort)0 : f2bf(tile[ic*57 + (w-1)]);
  }
}

// COO scatter into dense fp32 W [oc][k], duplicates sum via atomicAdd
__global__ void k_scatter(const int* __restrict__ idx, const float* __restrict__ val,
                          float* __restrict__ wd, int nnz) {
  int i = blockIdx.x*256 + threadIdx.x;
  if (i >= nnz) return;
  int id = idx[i];
  int oc = id / (ICN*9);
  int rem = id - oc*(ICN*9);
  int ic = rem / 9;
  int k9 = rem - ic*9;                                // kh*3+kw
  atomicAdd(wd + (size_t)oc*KTOT + k9*ICN + ic, val[i]);
}

// B in per-lane MFMA-fragment order for direct global->reg loads:
// 16B unit u = ((t*2+kh)*16 + wc*4 + f)*64 + lam holds
//   wd[oc = wc*64 + f*16 + (lam&15)][k = (t>>2)*256 + (t&3)*64 + kh*32 + (lam>>4)*8 .. +8]
__global__ void k_convert3(const float* __restrict__ wd, ushort* __restrict__ bm3) {
  int e = blockIdx.x*256 + threadIdx.x;      // 0 .. NT*2*16*64-1
  int lam = e & 63;
  int f   = (e >> 6) & 3;
  int wc  = (e >> 8) & 3;
  int kh  = (e >> 10) & 1;
  int t   = e >> 11;
  int oc  = wc*64 + f*16 + (lam & 15);
  int k   = (t >> 2)*256 + (t & 3)*64 + kh*32 + (lam >> 4)*8;
  const float* src = wd + (size_t)oc*KTOT + k;
  float4 v0 = *(const float4*)(src);
  float4 v1 = *(const float4*)(src + 4);
  us4 lo, hi;
  lo[0]=f2bf(v0.x); lo[1]=f2bf(v0.y); lo[2]=f2bf(v0.z); lo[3]=f2bf(v0.w);
  hi[0]=f2bf(v1.x); hi[1]=f2bf(v1.y); hi[2]=f2bf(v1.z); hi[3]=f2bf(v1.w);
  ushort* dst = bm3 + (size_t)e*8;
  *(us4*)(dst) = lo; *(us4*)(dst+4) = hi;
}

// ------ 256x256 implicit-GEMM: A via LDS (dbuf), B global->registers --------
// All 16 A ds_reads front-loaded at tile start into 4 static reg quads;
// counted lgkm(12/8/4/0) before each MFMA burst -> only burst 0 can stall.
// vmcnt FIFO (per wave), steady state entering tile t: [bvA 4].
//   +bvB 4, +stageAu0 2 -> VMW(6) drains bvA
//   +stageAu1 2
//   +bvA(t+1) 4         -> VMW(8) drains bvB
//   tile end            -> VMW(4) drains both A stage units; BAR; swap.
// Never vmcnt(0) in main loop.  All waits carry sched_barrier(0) (rule #18).

#define GLD(gsrc, ldst) __builtin_amdgcn_global_load_lds( \
    (const __attribute__((address_space(1))) void*)(gsrc), \
    (__attribute__((address_space(3))) void*)(ldst), 16, 0, 0)
#define BAR()  asm volatile("s_barrier" ::: "memory")
#define VMW(N) do { asm volatile("s_waitcnt vmcnt(" #N ")" ::: "memory"); \
                    __builtin_amdgcn_sched_barrier(0); } while (0)
#define LGKM(N) do { asm volatile("s_waitcnt lgkmcnt(" #N ")" ::: "memory"); \
                     __builtin_amdgcn_sched_barrier(0); } while (0)

#define STAGE_AU(T1, U) do { \
    const int t4_ = (T1) >> 2; const int khh_ = t4_/3, khw_ = t4_ - khh_*3; \
    const int koff_ = (khh_*HP + khw_)*256 + (((T1) & 3) << 6); \
    ushort* d_ = &Ab[(((T1)&1)*16384) + (U)*8192]; \
    GLD(xp + ((U) ? srcA10 : srcA00) + koff_, d_ + ldsOff0); \
    GLD(xp + ((U) ? srcA11 : srcA01) + koff_, d_ + ldsOff1); } while (0)

// B fragment loads: 4 x global_load_dwordx4 (contiguous 1KB runs, L2 hit)
#define GLB(DST, VOFF) \
    asm volatile("global_load_dwordx4 %0, %4, %5 offset:0\n\t" \
                 "global_load_dwordx4 %1, %4, %5 offset:1024\n\t" \
                 "global_load_dwordx4 %2, %4, %5 offset:2048\n\t" \
                 "global_load_dwordx4 %3, %4, %5 offset:3072" \
                 : "=&v"(DST[0]), "=&v"(DST[1]), "=&v"(DST[2]), "=&v"(DST[3]) \
                 : "v"(VOFF), "s"(bm3) : "memory")

#define LOADA_TO(DST, KH, MH, C) do { \
    unsigned a_ = ((KH) ? aL1v : aL0v) + (unsigned)((C)*32768 + (MH)*8192); \
    asm volatile("ds_read_b128 %0, %4 offset:0\n\t" \
                 "ds_read_b128 %1, %4 offset:2048\n\t" \
                 "ds_read_b128 %2, %4 offset:4096\n\t" \
                 "ds_read_b128 %3, %4 offset:6144" \
                 : "=&v"(DST[0]), "=&v"(DST[1]), "=&v"(DST[2]), "=&v"(DST[3]) \
                 : "v"(a_)); } while (0)

#define MFMA16(MH, AV, BV) do { \
    __builtin_amdgcn_s_setprio(1); \
    _Pragma("unroll") \
    for (int f_ = 0; f_ < 4; ++f_) { \
      _Pragma("unroll") \
      for (int n_ = 0; n_ < 4; ++n_) \
        acc[(MH)*4+f_][n_] = __builtin_amdgcn_mfma_f32_16x16x32_bf16( \
            AV[f_], BV[n_], acc[(MH)*4+f_][n_], 0, 0, 0); \
    } \
    __builtin_amdgcn_s_setprio(0); } while (0)

__global__ __launch_bounds__(512, 2) void k_gemm8(const ushort* __restrict__ xp,
                                                  const ushort* __restrict__ bm3,
                                                  const float* __restrict__ bias,
                                                  float* __restrict__ out) {
  __shared__ __align__(128) ushort Ab[2*2*128*64];   // 64 KB (A only)

  const int tid = threadIdx.x;
  const int lam = tid & 63;
  const int wv  = tid >> 6;            // 0..7
  const int wr  = wv >> 2;             // 0..1  (M half -> A unit)
  const int wc  = wv & 3;              // 0..3  (N quarter)
  const int la  = lam & 15;
  const int m0  = blockIdx.x * 256;

  const unsigned AbB = (unsigned)(uintptr_t)(__attribute__((address_space(3))) char*)Ab;

  // A read bases: byte addr = AbB + buf*32768 + u*16384 + mh*8192 + r*128 + p*16,
  // r = f*16+la, p = (kh*4 + oq) ^ (la&7), oq = lam>>4.
  const int q0 = (lam >> 4) ^ (la & 7);
  const unsigned aL0v = AbB + wr*16384 + la*128 + q0*16;
  const unsigned aL1v = AbB + wr*16384 + la*128 + (q0 ^ 4)*16;

  // B voffset base for this wave/lane (within bm3): + t*32768 + kh*16384
  const unsigned wcB = wc*4096 + lam*16;

  // A staging lane geometry (per wave 2 instrs of 64 slots)
  const int ldsOff0 = (0*8 + wv)*512;          // ushort offsets, wave-uniform
  const int ldsOff1 = (1*8 + wv)*512;
  // A: unit u, instr i: row r = (i*8+wv)*8 + (lam>>3); phys octet p = lam&7;
  // logical octet o = p ^ (r&7) = (lam&7) ^ (lam>>3).
  int srcA00, srcA01, srcA10, srcA11;
  {
    const int oA = (lam & 7) ^ (lam >> 3);
    int m, n, rem, oh, ow, r;
    r = (0*8 + wv)*8 + (lam >> 3);
    m = m0 + 0*128 + r; n = m/3136; rem = m - n*3136; oh = rem/56; ow = rem - oh*56;
    srcA00 = (n*SPAT + oh*HP + ow)*ICN + oA*8;
    r = (1*8 + wv)*8 + (lam >> 3);
    m = m0 + 0*128 + r; n = m/3136; rem = m - n*3136; oh = rem/56; ow = rem - oh*56;
    srcA01 = (n*SPAT + oh*HP + ow)*ICN + oA*8;
    r = (0*8 + wv)*8 + (lam >> 3);
    m = m0 + 1*128 + r; n = m/3136; rem = m - n*3136; oh = rem/56; ow = rem - oh*56;
    srcA10 = (n*SPAT + oh*HP + ow)*ICN + oA*8;
    r = (1*8 + wv)*8 + (lam >> 3);
    m = m0 + 1*128 + r; n = m/3136; rem = m - n*3136; oh = rem/56; ow = rem - oh*56;
    srcA11 = (n*SPAT + oh*HP + ow)*ICN + oA*8;
  }

  f32x4 acc[8][4];
#pragma unroll
  for (int a = 0; a < 8; ++a)
#pragma unroll
    for (int b = 0; b < 4; ++b) acc[a][b] = (f32x4){0.f, 0.f, 0.f, 0.f};

  // static register names only (rule #20)
  bf16x8 av00_[4], av01_[4], av10_[4], av11_[4], bvA_[4], bvB_[4];

  // prologue: stage A(0), load B(0,kh0); VMW(4) drains the 4 stage instrs
  STAGE_AU(0, 0); STAGE_AU(0, 1);
  GLB(bvA_, wcB);
  VMW(4);
  BAR();

  for (int t = 0; t < NT-1; ++t) {
    const int c = t & 1;
    const unsigned vb = (unsigned)t*32768 + wcB;
    // front-load ALL 16 A ds_reads for this tile
    LOADA_TO(av00_, 0, 0, c); LOADA_TO(av01_, 0, 1, c);
    LOADA_TO(av10_, 1, 0, c); LOADA_TO(av11_, 1, 1, c);
    // B(t,kh1) + stage A-u0(t+1)
    GLB(bvB_, vb + 16384);
    STAGE_AU(t+1, 0);
    VMW(6);                    // bvA ready
    LGKM(12);                  // av00 ready
    MFMA16(0, av00_, bvA_);
    STAGE_AU(t+1, 1);
    LGKM(8);                   // av01 ready
    MFMA16(1, av01_, bvA_);
    GLB(bvA_, vb + 32768);     // B(t+1,kh0)
    VMW(8);                    // bvB ready
    LGKM(4);                   // av10 ready
    MFMA16(0, av10_, bvB_);
    LGKM(0);                   // av11 ready
    MFMA16(1, av11_, bvB_);
    VMW(4);                    // A(t+1) stage units landed; bvA(t+1) in flight
    BAR();
  }

  // peeled last tile (t = NT-1): no staging
  {
    const int c = (NT-1) & 1;
    const unsigned vb = (unsigned)(NT-1)*32768 + wcB;
    LOADA_TO(av00_, 0, 0, c); LOADA_TO(av01_, 0, 1, c);
    LOADA_TO(av10_, 1, 0, c); LOADA_TO(av11_, 1, 1, c);
    GLB(bvB_, vb + 16384);
    VMW(4);                    // bvA ready (bvB outstanding)
    LGKM(12);
    MFMA16(0, av00_, bvA_);
    LGKM(8);
    MFMA16(1, av01_, bvA_);
    VMW(0);                    // bvB ready
    LGKM(4);
    MFMA16(0, av10_, bvB_);
    LGKM(0);
    MFMA16(1, av11_, bvB_);
  }

  // epilogue: lane l -> col(oc) = la, rows m = base + (l>>4)*4 + j
#pragma unroll
  for (int nn = 0; nn < 4; ++nn) {
    int oc = wc*64 + nn*16 + la;
    float bvs = bias[oc];
#pragma unroll
    for (int mf = 0; mf < 8; ++mf) {
      int m = m0 + wr*128 + mf*16 + ((lam >> 4) << 2);
      int n = m / 3136;
      int rem = m - n*3136;     // float4 never straddles n (3136 % 4 == 0)
      float4 o;
      o.x = acc[mf][nn][0] + bvs;
      o.y = acc[mf][nn][1] + bvs;
      o.z = acc[mf][nn][2] + bvs;
      o.w = acc[mf][nn][3] + bvs;
      *(float4*)(out + ((size_t)(n*OCN + oc))*3136 + rem) = o;
    }
  }
}

extern "C" void kernel_launch(void* const* d_in, const int* in_sizes, int n_in,
                              void* d_out, int out_size, void* d_ws, size_t ws_size,
                              hipStream_t stream) {
  const float* x    = (const float*)d_in[0];
  const float* wval = (const float*)d_in[1];
  const int*   widx = (const int*)d_in[2];
  const float* bias = (const float*)d_in[3];
  float* out = (float*)d_out;
  const int nnz = in_sizes[1];

  char* ws = (char*)d_ws;
  ushort* xp  = (ushort*)ws;                              // 55.1 MB
  float*  wd  = (float*)(ws + XP_BYTES);                  // 2.36 MB
  ushort* bm3 = (ushort*)(ws + XP_BYTES + WD_BYTES);      // 1.125 MB (frag-order B)

  hipMemsetAsync(wd, 0, WD_BYTES, stream);
  k_transpose<<<dim3(HP, NBATCH), 256, 0, stream>>>(x, xp);
  k_scatter<<<dim3((nnz + 255)/256), 256, 0, stream>>>(widx, wval, wd, nnz);
  k_convert3<<<dim3((NT*2*16*64)/256), 256, 0, stream>>>(wd, bm3);
  k_gemm8<<<dim3(MTOT/256), 512, 0, stream>>>(xp, bm3, bias, out);
}

// Round 10
// 160.298 us; speedup vs baseline: 1.1425x; 1.1425x over previous
//
#include <hip/hip_runtime.h>

typedef unsigned short ushort;
typedef __attribute__((ext_vector_type(8))) short bf16x8;
typedef __attribute__((ext_vector_type(4))) float f32x4;
typedef __attribute__((ext_vector_type(4))) ushort us4;

#define NBATCH 32
#define ICN 256
#define OCN 256
#define HSZ 56
#define WSZ 56
#define HP 58
#define SPAT (HP*HP)            /* 3364 */
#define KTOT 2304               /* 9*256, k = (kh*3+kw)*256 + ic */
#define MTOT (NBATCH*HSZ*WSZ)   /* 100352 */
#define NT   (KTOT/64)          /* 36 K-tiles of BK=64 */

#define XP_BYTES ((size_t)NBATCH*SPAT*ICN*2)    /* 55,115,776 */
#define WD_BYTES ((size_t)OCN*KTOT*4)           /* 2,359,296  */

__device__ __forceinline__ ushort f2bf(float f) {
  union { float f; unsigned u; } c; c.f = f;
  unsigned r = c.u + 0x7FFFu + ((c.u >> 16) & 1u);
  return (ushort)(r >> 16);
}

// x [N][IC][56][56] f32 -> xp [N][58][58][IC] bf16, halo rows/cols written as 0.
// bf16 LDS tile [w][ic] stride 264 -> us4 (8B/lane) coalesced writes.
__global__ void k_transpose(const float* __restrict__ x, ushort* __restrict__ xp) {
  __shared__ ushort t2[WSZ*264];   // 29.6 KB; stride 264 (528B, 8B-aligned rows)
  int h = blockIdx.x, n = blockIdx.y;          // h = padded row 0..57
  ushort* dst = xp + ((size_t)n*SPAT + (size_t)h*HP)*ICN;
  if (h == 0 || h == HP-1) {
    for (int e = threadIdx.x; e < HP*ICN/4; e += 256) ((us4*)dst)[e] = (us4){0,0,0,0};
    return;
  }
  const float* src = x + ((size_t)n*ICN*HSZ*WSZ) + (size_t)(h-1)*WSZ;
  for (int e = threadIdx.x; e < ICN*WSZ; e += 256) {
    int ic = e / WSZ, w = e - ic*WSZ;                 // w fastest -> coalesced read
    t2[w*264 + ic] = f2bf(src[(size_t)ic*(HSZ*WSZ) + w]);
  }
  __syncthreads();
  for (int e4 = threadIdx.x; e4 < HP*ICN/4; e4 += 256) {  // e4 = wp*64 + ic4
    int wp = e4 >> 6, ic4 = (e4 & 63) << 2;
    us4 v = (wp == 0 || wp == HP-1) ? (us4){0,0,0,0}
                                    : *(const us4*)&t2[(wp-1)*264 + ic4];
    ((us4*)dst)[e4] = v;
  }
}

// COO scatter into dense fp32 W [oc][k], duplicates sum via atomicAdd
__global__ void k_scatter(const int* __restrict__ idx, const float* __restrict__ val,
                          float* __restrict__ wd, int nnz) {
  int i = blockIdx.x*256 + threadIdx.x;
  if (i >= nnz) return;
  int id = idx[i];
  int oc = id / (ICN*9);
  int rem = id - oc*(ICN*9);
  int ic = rem / 9;
  int k9 = rem - ic*9;                                // kh*3+kw
  atomicAdd(wd + (size_t)oc*KTOT + k9*ICN + ic, val[i]);
}

// B in per-lane MFMA-fragment order for direct global->reg loads:
// 16B unit u = ((t*2+kh)*16 + wc*4 + f)*64 + lam holds
//   wd[oc = wc*64 + f*16 + (lam&15)][k = (t>>2)*256 + (t&3)*64 + kh*32 + (lam>>4)*8 .. +8]
__global__ void k_convert3(const float* __restrict__ wd, ushort* __restrict__ bm3) {
  int e = blockIdx.x*256 + threadIdx.x;      // 0 .. NT*2*16*64-1
  int lam = e & 63;
  int f   = (e >> 6) & 3;
  int wc  = (e >> 8) & 3;
  int kh  = (e >> 10) & 1;
  int t   = e >> 11;
  int oc  = wc*64 + f*16 + (lam & 15);
  int k   = (t >> 2)*256 + (t & 3)*64 + kh*32 + (lam >> 4)*8;
  const float* src = wd + (size_t)oc*KTOT + k;
  float4 v0 = *(const float4*)(src);
  float4 v1 = *(const float4*)(src + 4);
  us4 lo, hi;
  lo[0]=f2bf(v0.x); lo[1]=f2bf(v0.y); lo[2]=f2bf(v0.z); lo[3]=f2bf(v0.w);
  hi[0]=f2bf(v1.x); hi[1]=f2bf(v1.y); hi[2]=f2bf(v1.z); hi[3]=f2bf(v1.w);
  ushort* dst = bm3 + (size_t)e*8;
  *(us4*)(dst) = lo; *(us4*)(dst+4) = hi;
}

// --- 256x256 implicit-GEMM: triple-buffered A, distance-2 staging ----------
// A(t+1) resident THROUGHOUT tile t -> reads for tile t+1 bursts 0/1 issue
// under tile t's last MFMA bursts; each tile opens with immediate MFMA.
// Per tile t (bursts b0..b3 = (kh0,mh0)(kh0,mh1)(kh1,mh0)(kh1,mh1)):
//   b0: read q2(t,bf0) | GLB bvB(t) | VMW(4)[bvA+stage(t+1) landed] | LGKM(8) | MFMA q0
//   b1: read q3(t,bf0) | stage u0(t+2)->bf2 | LGKM(8) | MFMA q1
//   MIDBAR  (all waves passed b0-VMW -> stage(t+1) landed block-wide)
//   b2: read q0(t+1,bf1) | stage u1(t+2)->bf2 | VMW(4)[bvB landed] | LGKM(8) | MFMA q2
//   b3: read q1(t+1,bf1) | GLB bvA(t+1) | LGKM(8) | MFMA q3
//   ENDBAR  (all buf(t-1) reads done before it -> next tile's staging is safe)
// vmcnt FIFO entering t: [u0(t+1)2, u1(t+1)2, bvA(t)4] = 8.  Never vmcnt(0)
// in main loop.  ds FIFO at every wait = 12 -> uniform lgkmcnt(8).

#define GLD(gsrc, ldst) __builtin_amdgcn_global_load_lds( \
    (const __attribute__((address_space(1))) void*)(gsrc), \
    (__attribute__((address_space(3))) void*)(ldst), 16, 0, 0)
#define BAR()  asm volatile("s_barrier" ::: "memory")
#define VMW(N) do { asm volatile("s_waitcnt vmcnt(" #N ")" ::: "memory"); \
                    __builtin_amdgcn_sched_barrier(0); } while (0)
#define LGKM(N) do { asm volatile("s_waitcnt lgkmcnt(" #N ")" ::: "memory"); \
                     __builtin_amdgcn_sched_barrier(0); } while (0)

#define STAGE_AU(T1, U, BF) do { \
    const int t4_ = (T1) >> 2; const int khh_ = t4_/3, khw_ = t4_ - khh_*3; \
    const int koff_ = (khh_*HP + khw_)*256 + (((T1) & 3) << 6); \
    ushort* d_ = &Ab[(BF)*16384 + (U)*8192]; \
    GLD(xp + ((U) ? srcA10 : srcA00) + koff_, d_ + ldsOff0); \
    GLD(xp + ((U) ? srcA11 : srcA01) + koff_, d_ + ldsOff1); } while (0)

// B fragment loads: 4 x global_load_dwordx4 (contiguous 1KB runs, L2 hit)
#define GLB(DST, VOFF) \
    asm volatile("global_load_dwordx4 %0, %4, %5 offset:0\n\t" \
                 "global_load_dwordx4 %1, %4, %5 offset:1024\n\t" \
                 "global_load_dwordx4 %2, %4, %5 offset:2048\n\t" \
                 "global_load_dwordx4 %3, %4, %5 offset:3072" \
                 : "=&v"(DST[0]), "=&v"(DST[1]), "=&v"(DST[2]), "=&v"(DST[3]) \
                 : "v"(VOFF), "s"(bm3) : "memory")

// BFB = buffer byte offset (bf*32768)
#define LOADA_TO(DST, KH, MH, BFB) do { \
    unsigned a_ = ((KH) ? aL1v : aL0v) + (unsigned)((BFB) + (MH)*8192); \
    asm volatile("ds_read_b128 %0, %4 offset:0\n\t" \
                 "ds_read_b128 %1, %4 offset:2048\n\t" \
                 "ds_read_b128 %2, %4 offset:4096\n\t" \
                 "ds_read_b128 %3, %4 offset:6144" \
                 : "=&v"(DST[0]), "=&v"(DST[1]), "=&v"(DST[2]), "=&v"(DST[3]) \
                 : "v"(a_)); } while (0)

#define MFMA16(MH, AV, BV) do { \
    __builtin_amdgcn_s_setprio(1); \
    _Pragma("unroll") \
    for (int f_ = 0; f_ < 4; ++f_) { \
      _Pragma("unroll") \
      for (int n_ = 0; n_ < 4; ++n_) \
        acc[(MH)*4+f_][n_] = __builtin_amdgcn_mfma_f32_16x16x32_bf16( \
            AV[f_], BV[n_], acc[(MH)*4+f_][n_], 0, 0, 0); \
    } \
    __builtin_amdgcn_s_setprio(0); } while (0)

__global__ __launch_bounds__(512, 2) void k_gemm8(const ushort* __restrict__ xp,
                                                  const ushort* __restrict__ bm3,
                                                  const float* __restrict__ bias,
                                                  float* __restrict__ out) {
  __shared__ __align__(128) ushort Ab[3*16384];   // 96 KB: 3 x [2 u][128 r][64 k]

  const int tid = threadIdx.x;
  const int lam = tid & 63;
  const int wv  = tid >> 6;            // 0..7
  const int wr  = wv >> 2;             // 0..1  (M half -> A unit)
  const int wc  = wv & 3;              // 0..3  (N quarter)
  const int la  = lam & 15;
  const int m0  = blockIdx.x * 256;

  const unsigned AbB = (unsigned)(uintptr_t)(__attribute__((address_space(3))) char*)Ab;

  // A read bases (within a buffer): + bf*32768 + mh*8192 at use.
  // byte = u(wr)*16384 + r*128 + p*16, r = f*16+la, p = (kh*4+oq)^(la&7), oq=lam>>4.
  const int q0 = (lam >> 4) ^ (la & 7);
  const unsigned aL0v = AbB + wr*16384 + la*128 + q0*16;
  const unsigned aL1v = AbB + wr*16384 + la*128 + (q0 ^ 4)*16;

  // B voffset base (within bm3): + t*32768 + kh*16384
  const unsigned wcB = wc*4096 + lam*16;

  // A staging lane geometry (per wave 2 instrs of 64 slots)
  const int ldsOff0 = (0*8 + wv)*512;          // ushort offsets, wave-uniform
  const int ldsOff1 = (1*8 + wv)*512;
  // A: unit u, instr i: row r = (i*8+wv)*8 + (lam>>3); phys octet p = lam&7;
  // logical octet o = p ^ (r&7) = (lam&7) ^ (lam>>3).
  int srcA00, srcA01, srcA10, srcA11;
  {
    const int oA = (lam & 7) ^ (lam >> 3);
    int m, n, rem, oh, ow, r;
    r = (0*8 + wv)*8 + (lam >> 3);
    m = m0 + 0*128 + r; n = m/3136; rem = m - n*3136; oh = rem/56; ow = rem - oh*56;
    srcA00 = (n*SPAT + oh*HP + ow)*ICN + oA*8;
    r = (1*8 + wv)*8 + (lam >> 3);
    m = m0 + 0*128 + r; n = m/3136; rem = m - n*3136; oh = rem/56; ow = rem - oh*56;
    srcA01 = (n*SPAT + oh*HP + ow)*ICN + oA*8;
    r = (0*8 + wv)*8 + (lam >> 3);
    m = m0 + 1*128 + r; n = m/3136; rem = m - n*3136; oh = rem/56; ow = rem - oh*56;
    srcA10 = (n*SPAT + oh*HP + ow)*ICN + oA*8;
    r = (1*8 + wv)*8 + (lam >> 3);
    m = m0 + 1*128 + r; n = m/3136; rem = m - n*3136; oh = rem/56; ow = rem - oh*56;
    srcA11 = (n*SPAT + oh*HP + ow)*ICN + oA*8;
  }

  f32x4 acc[8][4];
#pragma unroll
  for (int a = 0; a < 8; ++a)
#pragma unroll
    for (int b = 0; b < 4; ++b) acc[a][b] = (f32x4){0.f, 0.f, 0.f, 0.f};

  // static register names only (rule #20)
  bf16x8 avq0_[4], avq1_[4], avq2_[4], avq3_[4], bvA_[4], bvB_[4];

  // prologue: stage A(0)->buf0, A(1)->buf1; B(0,kh0); preload bursts 0/1 of t=0
  STAGE_AU(0, 0, 0); STAGE_AU(0, 1, 0);
  STAGE_AU(1, 0, 1); STAGE_AU(1, 1, 1);
  GLB(bvA_, wcB);
  VMW(4);                      // A(0) landed; [A(1)u0 2, A(1)u1 2, bvA 4] = 8 left
  BAR();
  LOADA_TO(avq0_, 0, 0, 0); LOADA_TO(avq1_, 0, 1, 0);

  int bf0 = 0, bf1 = 1, bf2 = 2;
  for (int t = 0; t < NT-2; ++t) {
    const int b0b = bf0*32768, b1b = bf1*32768;
    const unsigned vb = (unsigned)t*32768 + wcB;
    // b0
    LOADA_TO(avq2_, 1, 0, b0b);
    GLB(bvB_, vb + 16384);
    VMW(4);                    // bvA ready; stage(t+1) landed (this wave)
    LGKM(8);                   // avq0 ready
    MFMA16(0, avq0_, bvA_);
    // b1
    LOADA_TO(avq3_, 1, 1, b0b);
    STAGE_AU(t+2, 0, bf2);
    LGKM(8);                   // avq1 ready
    MFMA16(1, avq1_, bvA_);
    BAR();                     // MID: all waves' stage(t+1) landed block-wide
    // b2
    LOADA_TO(avq0_, 0, 0, b1b);
    STAGE_AU(t+2, 1, bf2);
    VMW(4);                    // bvB ready
    LGKM(8);                   // avq2 ready
    MFMA16(0, avq2_, bvB_);
    // b3
    LOADA_TO(avq1_, 0, 1, b1b);
    GLB(bvA_, vb + 32768);     // B(t+1, kh0)
    LGKM(8);                   // avq3 ready
    MFMA16(1, avq3_, bvB_);
    BAR();                     // END: buf(t-1) reads all done before this
    int bt = bf0; bf0 = bf1; bf1 = bf2; bf2 = bt;
  }

  // peel t = NT-2: no staging (t+2 out of range)
  {
    const int t = NT-2;
    const int b0b = bf0*32768, b1b = bf1*32768;
    const unsigned vb = (unsigned)t*32768 + wcB;
    LOADA_TO(avq2_, 1, 0, b0b);
    GLB(bvB_, vb + 16384);
    VMW(4);                    // bvA + stage(NT-1) landed
    LGKM(8);
    MFMA16(0, avq0_, bvA_);
    LOADA_TO(avq3_, 1, 1, b0b);
    LGKM(8);
    MFMA16(1, avq1_, bvA_);
    BAR();                     // MID
    LOADA_TO(avq0_, 0, 0, b1b);
    VMW(0);                    // bvB ready (tail: only bvB outstanding)
    LGKM(8);
    MFMA16(0, avq2_, bvB_);
    LOADA_TO(avq1_, 0, 1, b1b);
    GLB(bvA_, vb + 32768);     // B(NT-1, kh0)
    LGKM(8);
    MFMA16(1, avq3_, bvB_);
    BAR();                     // END
    int bt = bf0; bf0 = bf1; bf1 = bf2; bf2 = bt;
  }

  // peel t = NT-1: no staging, no next-tile reads
  {
    const int t = NT-1;
    const int b0b = bf0*32768;
    const unsigned vb = (unsigned)t*32768 + wcB;
    LOADA_TO(avq2_, 1, 0, b0b);
    GLB(bvB_, vb + 16384);
    VMW(4);                    // bvA ready
    LGKM(8);
    MFMA16(0, avq0_, bvA_);
    LOADA_TO(avq3_, 1, 1, b0b);
    LGKM(8);
    MFMA16(1, avq1_, bvA_);
    VMW(0);                    // bvB ready
    LGKM(4);
    MFMA16(0, avq2_, bvB_);
    LGKM(0);
    MFMA16(1, avq3_, bvB_);
  }

  // epilogue: lane l -> col(oc) = la, rows m = base + (l>>4)*4 + j
#pragma unroll
  for (int nn = 0; nn < 4; ++nn) {
    int oc = wc*64 + nn*16 + la;
    float bvs = bias[oc];
#pragma unroll
    for (int mf = 0; mf < 8; ++mf) {
      int m = m0 + wr*128 + mf*16 + ((lam >> 4) << 2);
      int n = m / 3136;
      int rem = m - n*3136;     // float4 never straddles n (3136 % 4 == 0)
      float4 o;
      o.x = acc[mf][nn][0] + bvs;
      o.y = acc[mf][nn][1] + bvs;
      o.z = acc[mf][nn][2] + bvs;
      o.w = acc[mf][nn][3] + bvs;
      *(float4*)(out + ((size_t)(n*OCN + oc))*3136 + rem) = o;
    }
  }
}

extern "C" void kernel_launch(void* const* d_in, const int* in_sizes, int n_in,
                              void* d_out, int out_size, void* d_ws, size_t ws_size,
                              hipStream_t stream) {
  const float* x    = (const float*)d_in[0];
  const float* wval = (const float*)d_in[1];
  const int*   widx = (const int*)d_in[2];
  const float* bias = (const float*)d_in[3];
  float* out = (float*)d_out;
  const int nnz = in_sizes[1];

  char* ws = (char*)d_ws;
  ushort* xp  = (ushort*)ws;                              // 55.1 MB
  float*  wd  = (float*)(ws + XP_BYTES);                  // 2.36 MB
  ushort* bm3 = (ushort*)(ws + XP_BYTES + WD_BYTES);      // 1.125 MB (frag-order B)

  hipMemsetAsync(wd, 0, WD_BYTES, stream);
  k_transpose<<<dim3(HP, NBATCH), 256, 0, stream>>>(x, xp);
  k_scatter<<<dim3((nnz + 255)/256), 256, 0, stream>>>(widx, wval, wd, nnz);
  k_convert3<<<dim3((NT*2*16*64)/256), 256, 0, stream>>>(wd, bm3);
  k_gemm8<<<dim3(MTOT/256), 512, 0, stream>>>(xp, bm3, bias, out);
}